// Round 2
// baseline (547.609 us; speedup 1.0000x reference)
//
#include <hip/hip_runtime.h>

// CoarseMatching on MI355X. Round 2.
// k_sim2: SGPR-broadcast f32 GEMM (A rows via s_load uniform broadcast, B coalesced,
//         no LDS, no barriers, 2500 independent wave-tiles of 32i x 64j).
// k_heat2: both directions fused, 256-thread blocks, C-split + shuffle combine.
// k_fuse: fuse01+fuse10 merged. k_unpatch2: both tensors in one dispatch.

#define N_B   2
#define C_DIM 256
#define G0N   1600
#define GW    40
#define L0N   6400
#define W_F   80
#define TK    8

// ---------------- K1: sim = p0^T p1 / C, plus simT. SGPR-broadcast GEMM ----------------
// Wave-tile: 32 rows(i) x 64 cols(j). 2 n x 50 it x 25 jt = 2500 tiles, 4 waves/block.
__global__ __launch_bounds__(256) void k_sim2(const float* __restrict__ p0,
                                              const float* __restrict__ p1,
                                              float* __restrict__ sim,
                                              float* __restrict__ simT) {
  const int w    = threadIdx.x >> 6;
  const int lane = threadIdx.x & 63;
  const int tile = blockIdx.x * 4 + w;          // 0..2499
  const int n    = tile / 1250;
  const int rem  = tile - n * 1250;
  const int it   = rem / 25, jt = rem - it * 25;
  const int i0   = it * 32, j0 = jt * 64;

  const float* A = p0 + (size_t)n * C_DIM * G0N + i0;         // uniform address stream
  const float* B = p1 + (size_t)n * C_DIM * G0N + j0 + lane;  // coalesced per-lane

  float acc[32];
#pragma unroll
  for (int r = 0; r < 32; ++r) acc[r] = 0.f;

#pragma unroll 2
  for (int k = 0; k < C_DIM; ++k) {
    const float bv = B[(size_t)k * G0N];
    const float* Ak = A + (size_t)k * G0N;   // wave-uniform -> s_load broadcast
#pragma unroll
    for (int r = 0; r < 32; ++r) acc[r] = fmaf(Ak[r], bv, acc[r]);
  }

#pragma unroll
  for (int r = 0; r < 32; ++r) acc[r] *= (1.0f / 256.0f);

  float* simn  = sim  + (size_t)n * G0N * G0N;
  float* simTn = simT + (size_t)n * G0N * G0N;
  // sim rows: coalesced dword stores (64 lanes consecutive j)
#pragma unroll
  for (int r = 0; r < 32; ++r)
    simn[(size_t)(i0 + r) * G0N + j0 + lane] = acc[r];
  // simT row (j0+lane) holds exactly this lane's acc[] -> 8 b128 stores per lane
  float* trow = simTn + (size_t)(j0 + lane) * G0N + i0;
  const float4* av = (const float4*)acc;
#pragma unroll
  for (int c = 0; c < 8; ++c) *(float4*)(trow + c * 4) = av[c];
}

// ---------------- K2: top-8 per row (one wave / row), JAX tie-break ----------------
__global__ __launch_bounds__(256) void k_topk(const float* __restrict__ sim,
                                              const float* __restrict__ simT,
                                              int* __restrict__ i01,
                                              int* __restrict__ i10) {
  int wid  = (blockIdx.x * 256 + threadIdx.x) >> 6;  // 0..6399
  int lane = threadIdx.x & 63;
  int dir  = wid / (N_B * G0N);
  int r    = wid - dir * (N_B * G0N);
  const float* row = (dir ? simT : sim) + (size_t)r * G0N;
  int* out = (dir ? i10 : i01) + r * TK;

  float v[25];
#pragma unroll
  for (int tt = 0; tt < 25; ++tt) v[tt] = row[lane + 64 * tt];

#pragma unroll 1
  for (int k = 0; k < TK; ++k) {
    float best = -3.4e38f; int bidx = 0x7fffffff;
#pragma unroll
    for (int tt = 0; tt < 25; ++tt) {
      if (v[tt] > best) { best = v[tt]; bidx = lane + 64 * tt; }
    }
#pragma unroll
    for (int off = 1; off < 64; off <<= 1) {
      float ov = __shfl_xor(best, off);
      int   oi = __shfl_xor(bidx, off);
      if (ov > best || (ov == best && oi < bidx)) { best = ov; bidx = oi; }
    }
    if (lane == 0) out[k] = bidx;
#pragma unroll
    for (int tt = 0; tt < 25; ++tt)
      if (lane + 64 * tt == bidx) v[tt] = -3.4e38f;
  }
}

// ---------------- K3: pre-softmax heatmaps, both directions fused ----------------
// Block = 256 threads, one (d, n, g) per block. grid 6400.
__global__ __launch_bounds__(256) void k_heat2(const float* __restrict__ x0,
                                               const float* __restrict__ a01,
                                               const float* __restrict__ x1,
                                               const float* __restrict__ a10,
                                               float* __restrict__ h01p,
                                               float* __restrict__ h10p) {
  const int bid = blockIdx.x;
  const int d   = bid / 3200;
  const int ng  = bid - d * 3200;
  const float* x   = d ? x1  : x0;
  const float* att = d ? a10 : a01;
  float*       hp  = d ? h10p : h01p;
  const float* xp = x   + (size_t)ng * 4  * C_DIM;
  const float* ap = att + (size_t)ng * 32 * C_DIM;

  __shared__ float as[32][260];  // pad 260: b128 column reads hit all 32 banks evenly
  __shared__ float xs[4 * C_DIM];
  const int t = threadIdx.x;
#pragma unroll
  for (int j = 0; j < 8; ++j) {        // 2048 float4 units, 8 per thread, coalesced
    int f = t + j * 256;
    float4 v = *(const float4*)(ap + (size_t)f * 4);
    *(float4*)&as[f >> 6][(f & 63) * 4] = v;
  }
  {
    float4 v = *(const float4*)(xp + (size_t)t * 4);
    *(float4*)&xs[t * 4] = v;
  }
  __syncthreads();

  const int q = t >> 6;            // wave = q (0..3)
  const int lane = t & 63;
  const int k4 = lane & 31, ch = lane >> 5;
  const float* ar = &as[k4][ch * 128];
  const float* xr = &xs[q * C_DIM + ch * 128];   // broadcast (uniform per half-wave)
  float acc = 0.f;
#pragma unroll
  for (int c4 = 0; c4 < 32; ++c4) {
    float4 a  = *(const float4*)(ar + c4 * 4);
    float4 xv = *(const float4*)(xr + c4 * 4);
    acc += a.x * xv.x + a.y * xv.y + a.z * xv.z + a.w * xv.w;
  }
  acc += __shfl_xor(acc, 32);      // combine C halves

  float l = (acc * (1.0f / 256.0f)) / 0.1f;  // /C then /TEMP (reference order)
  float m = l;
#pragma unroll
  for (int off = 1; off < 32; off <<= 1) m = fmaxf(m, __shfl_xor(m, off));
  float e = expf(l - m);
  float s = e;
#pragma unroll
  for (int off = 1; off < 32; off <<= 1) s += __shfl_xor(s, off);
  if (ch == 0) hp[(size_t)ng * 128 + q * 32 + k4] = e / s;
}

// ---------------- K4: fused mutual heatmaps + argmax (both directions) ----------------
__global__ __launch_bounds__(256) void k_fuse(const float* __restrict__ h01p,
                                              const float* __restrict__ h10p,
                                              const int* __restrict__ i01,
                                              const int* __restrict__ i10,
                                              float* __restrict__ h01_out,
                                              float* __restrict__ h10_out,
                                              float* __restrict__ score_ws,
                                              int* __restrict__ jbest_ws,
                                              float* __restrict__ jbest_out,
                                              int* __restrict__ ibest_ws) {
  const int d   = blockIdx.x / 1600;
  const int sub = blockIdx.x - d * 1600;
  int idx = sub * 8 + (threadIdx.x >> 5);  // (n, l)
  int k4  = threadIdx.x & 31;
  int n = idx / L0N, l = idx - n * L0N;
  int rr = l / W_F, cc = l - rr * W_F;
  int g = (rr >> 1) * GW + (cc >> 1);
  int q = ((rr & 1) << 1) | (cc & 1);
  int k = k4 >> 2, gg = k4 & 3;

  if (d == 0) {
    int jc = i01[(n * G0N + g) * TK + k];
    const int* row10 = i10 + (n * G0N + jc) * TK;
    int kf = -1;
#pragma unroll
    for (int kp = 0; kp < 8; ++kp) if (row10[kp] == g) kf = kp;
    float m = 0.f;
    if (kf >= 0) m = h10p[((n * G0N + jc) * 4 + gg) * 32 + kf * 4 + q];
    float h = h01p[((n * G0N + g) * 4 + q) * 32 + k4];
    float val = h * m;
    h01_out[(size_t)idx * 32 + k4] = val;

    float best = val; int bi = k4;
#pragma unroll
    for (int off = 1; off < 32; off <<= 1) {
      float ov = __shfl_xor(best, off);
      int   oi = __shfl_xor(bi, off);
      if (ov > best || (ov == best && oi < bi)) { best = ov; bi = oi; }
    }
    if (k4 == 0) {
      score_ws[idx] = best;
      int kB = bi >> 2, gB = bi & 3;
      int jcB = i01[(n * G0N + g) * TK + kB];
      int jrow = jcB / GW;
      int jb = ((jrow * 2 + (gB >> 1)) * W_F) + (jcB - jrow * GW) * 2 + (gB & 1);
      if (rr < 2 || rr >= W_F - 2 || cc < 2 || cc >= W_F - 2) jb = 0;
      jbest_ws[idx]  = jb;
      jbest_out[idx] = (float)jb;
    }
  } else {
    int ic = i10[(n * G0N + g) * TK + k];
    const int* row01 = i01 + (n * G0N + ic) * TK;
    int kf = -1;
#pragma unroll
    for (int kp = 0; kp < 8; ++kp) if (row01[kp] == g) kf = kp;
    float m = 0.f;
    if (kf >= 0) m = h01p[((n * G0N + ic) * 4 + gg) * 32 + kf * 4 + q];
    float h = h10p[((n * G0N + g) * 4 + q) * 32 + k4];
    float val = h * m;
    h10_out[((size_t)n * 32 + k4) * L0N + l] = val;

    float best = val; int bi = k4;
#pragma unroll
    for (int off = 1; off < 32; off <<= 1) {
      float ov = __shfl_xor(best, off);
      int   oi = __shfl_xor(bi, off);
      if (ov > best || (ov == best && oi < bi)) { best = ov; bi = oi; }
    }
    if (k4 == 0) {
      int kB = bi >> 2, gB = bi & 3;
      int icB = i10[(n * G0N + g) * TK + kB];
      int irow = icB / GW;
      int ib = ((irow * 2 + (gB >> 1)) * W_F) + (icB - irow * GW) * 2 + (gB & 1);
      if (rr < 2 || rr >= W_F - 2 || cc < 2 || cc >= W_F - 2) ib = 0;
      ibest_ws[idx] = ib;
    }
  }
}

// ---------------- K5: bi-projection mask + masked scores ----------------
__global__ __launch_bounds__(256) void k_final(const float* __restrict__ score_ws,
                                               const int* __restrict__ jbest_ws,
                                               const int* __restrict__ ibest_ws,
                                               float* __restrict__ scores_out,
                                               float* __restrict__ mask_out) {
  int idx = blockIdx.x * 256 + threadIdx.x;
  if (idx >= N_B * L0N) return;
  int n = idx / L0N, l0 = idx - n * L0N;
  int jb = jbest_ws[idx];
  float sc = score_ws[idx];
  int biproj = ibest_ws[n * L0N + jb];
  bool mk = (biproj == l0) && (l0 != 0) && (sc > 0.2f);
  scores_out[idx] = mk ? sc : 0.f;
  mask_out[idx]   = mk ? 1.f : 0.f;
}

// ---------------- K6: unpatchify, both tensors in one dispatch ----------------
__global__ __launch_bounds__(256) void k_unpatch2(const float* __restrict__ x0,
                                                  const float* __restrict__ x1,
                                                  float* __restrict__ o0,
                                                  float* __restrict__ o1) {
  __shared__ float tile[32][33];
  int which = blockIdx.z >> 4;
  const float* x = which ? x1 : x0;
  float* out = which ? o1 : o0;
  int zz  = blockIdx.z & 15;
  int cc0 = blockIdx.x * 32;
  int r   = blockIdx.y;
  int n   = zz >> 3;
  int c0  = (zz & 7) * 32;
  int t = threadIdx.x;
  int sr = r & 1, ghr = r >> 1;
  int pos = t >> 5, cl = t & 31;
#pragma unroll
  for (int it = 0; it < 4; ++it) {
    int p = pos + it * 8;
    int cc = cc0 + p;
    if (cc < W_F) {
      int gg = ghr * GW + (cc >> 1);
      int qq = (sr << 1) | (cc & 1);
      tile[p][cl] = x[(((size_t)n * G0N + gg) * 4 + qq) * C_DIM + c0 + cl];
    }
  }
  __syncthreads();
  int co = t >> 5, p2 = t & 31;
#pragma unroll
  for (int it = 0; it < 4; ++it) {
    int c = c0 + co + it * 8;
    int cc = cc0 + p2;
    if (cc < W_F)
      out[(((size_t)n * C_DIM + c) * W_F + r) * W_F + cc] = tile[p2][co + it * 8];
  }
}

extern "C" void kernel_launch(void* const* d_in, const int* in_sizes, int n_in,
                              void* d_out, int out_size, void* d_ws, size_t ws_size,
                              hipStream_t stream) {
  const float* x0  = (const float*)d_in[0];
  const float* x1  = (const float*)d_in[1];
  const float* a01 = (const float*)d_in[2];
  const float* a10 = (const float*)d_in[3];
  const float* p0  = (const float*)d_in[4];
  const float* p1  = (const float*)d_in[5];
  float* out = (float*)d_out;

  float* ws       = (float*)d_ws;
  float* sim      = ws;                      // 2*1600*1600
  float* simT     = ws + 5120000;            // 2*1600*1600
  int*   i01      = (int*)(ws + 10240000);   // 2*1600*8
  int*   i10      = (int*)(ws + 10265600);
  float* h01p     = ws + 10291200;           // 2*1600*4*32
  float* h10p     = ws + 10700800;
  float* score_ws = ws + 11110400;           // 2*6400
  int*   jbest_ws = (int*)(ws + 11123200);
  int*   ibest_ws = (int*)(ws + 11136000);

  float* o_h01   = out;
  float* o_h10   = out + 409600;
  float* o_score = out + 819200;
  float* o_jbest = out + 832000;
  float* o_mask  = out + 844800;
  float* o_x08   = out + 857600;
  float* o_x18   = out + 4134400;

  k_sim2<<<625, 256, 0, stream>>>(p0, p1, sim, simT);
  k_topk<<<1600, 256, 0, stream>>>(sim, simT, i01, i10);
  k_heat2<<<6400, 256, 0, stream>>>(x0, a01, x1, a10, h01p, h10p);
  k_fuse<<<3200, 256, 0, stream>>>(h01p, h10p, i01, i10,
                                   o_h01, o_h10, score_ws, jbest_ws, o_jbest, ibest_ws);
  k_final<<<50, 256, 0, stream>>>(score_ws, jbest_ws, ibest_ws, o_score, o_mask);
  k_unpatch2<<<dim3(3, 80, 32), 256, 0, stream>>>(x0, x1, o_x08, o_x18);
}

// Round 3
// 408.142 us; speedup vs baseline: 1.3417x; 1.3417x over previous
//
#include <hip/hip_runtime.h>

// CoarseMatching on MI355X. Round 3.
// k_sim3: 128x128 f32 LDS GEMM, 8x8/thread (0.5 B LDS per FMA -> VALU-bound),
//         pad-132 LDS + split fragments (2-way bank alias only). 338 blocks.
// k_heat3: direct-global (no LDS/barrier), lane-streamed att rows, L1 line reuse.
// Rest unchanged from the passing round-2 kernels.

#define N_B   2
#define C_DIM 256
#define G0N   1600
#define GW    40
#define L0N   6400
#define W_F   80
#define TK    8

// ---------------- K1: sim = p0^T p1 / C (+ simT), 128x128 tile, 8x8/thread ----------------
__global__ __launch_bounds__(256) void k_sim3(const float* __restrict__ p0,
                                              const float* __restrict__ p1,
                                              float* __restrict__ sim,
                                              float* __restrict__ simT) {
  const int n  = blockIdx.z;
  const int i0 = blockIdx.y * 128;
  const int j0 = blockIdx.x * 128;
  const float* A = p0 + (size_t)n * C_DIM * G0N;  // [c][i]
  const float* B = p1 + (size_t)n * C_DIM * G0N;  // [c][j]
  __shared__ float As[16][132];  // pad 132: staging-write banks (4*row+col)%32 -> even
  __shared__ float Bs[16][132];
  const int t  = threadIdx.x;
  const int tx = t & 15, ty = t >> 4;
  const int srow = t >> 5;        // staging row 0..7 (+8 on second pass)
  const int scol = (t & 31) * 4;  // staging col 0..124

  float acc[8][8];
#pragma unroll
  for (int a = 0; a < 8; ++a)
#pragma unroll
    for (int b = 0; b < 8; ++b) acc[a][b] = 0.f;

  int ia = i0 + scol; if (ia > G0N - 4) ia = G0N - 4;  // clamp: stays 16B-aligned
  int ja = j0 + scol; if (ja > G0N - 4) ja = G0N - 4;

  for (int kc = 0; kc < C_DIM; kc += 16) {
#pragma unroll
    for (int p = 0; p < 2; ++p) {
      int row = srow + p * 8;
      int c = kc + row;
      float4 av = *(const float4*)(A + (size_t)c * G0N + ia);
      float4 bv = *(const float4*)(B + (size_t)c * G0N + ja);
      *(float4*)&As[row][scol] = av;
      *(float4*)&Bs[row][scol] = bv;
    }
    __syncthreads();
#pragma unroll
    for (int k = 0; k < 16; ++k) {
      float a[8], b[8];
      // split fragments: halves at col and 64+col, 16B granules -> 2-way alias max
      *(float4*)&a[0] = *(const float4*)&As[k][ty * 4];
      *(float4*)&a[4] = *(const float4*)&As[k][64 + ty * 4];
      *(float4*)&b[0] = *(const float4*)&Bs[k][tx * 4];
      *(float4*)&b[4] = *(const float4*)&Bs[k][64 + tx * 4];
#pragma unroll
      for (int ii = 0; ii < 8; ++ii)
#pragma unroll
        for (int jj = 0; jj < 8; ++jj) acc[ii][jj] = fmaf(a[ii], b[jj], acc[ii][jj]);
    }
    __syncthreads();
  }

#pragma unroll
  for (int ii = 0; ii < 8; ++ii)
#pragma unroll
    for (int jj = 0; jj < 8; ++jj) acc[ii][jj] *= (1.0f / 256.0f);

  float* simn  = sim  + (size_t)n * G0N * G0N;
  float* simTn = simT + (size_t)n * G0N * G0N;
  // sim: rows i, contiguous float4 in j. i/j offsets: half h adds 64.
#pragma unroll
  for (int ii = 0; ii < 8; ++ii) {
    int io = (ii < 4) ? (ty * 4 + ii) : (64 + ty * 4 + ii - 4);
    int i = i0 + io;
    if (i < G0N) {
#pragma unroll
      for (int h = 0; h < 2; ++h) {
        int j = j0 + h * 64 + tx * 4;
        if (j < G0N) {
          float4 v = make_float4(acc[ii][h*4], acc[ii][h*4+1], acc[ii][h*4+2], acc[ii][h*4+3]);
          *(float4*)(simn + (size_t)i * G0N + j) = v;
        }
      }
    }
  }
  // simT: rows j, contiguous float4 in i (thread's i groups are 4-contiguous).
#pragma unroll
  for (int jj = 0; jj < 8; ++jj) {
    int jo = (jj < 4) ? (tx * 4 + jj) : (64 + tx * 4 + jj - 4);
    int j = j0 + jo;
    if (j < G0N) {
#pragma unroll
      for (int h = 0; h < 2; ++h) {
        int i = i0 + h * 64 + ty * 4;
        if (i < G0N) {
          float4 v = make_float4(acc[h*4][jj], acc[h*4+1][jj], acc[h*4+2][jj], acc[h*4+3][jj]);
          *(float4*)(simTn + (size_t)j * G0N + i) = v;
        }
      }
    }
  }
}

// ---------------- K2: top-8 per row (one wave / row), JAX tie-break ----------------
__global__ __launch_bounds__(256) void k_topk(const float* __restrict__ sim,
                                              const float* __restrict__ simT,
                                              int* __restrict__ i01,
                                              int* __restrict__ i10) {
  int wid  = (blockIdx.x * 256 + threadIdx.x) >> 6;  // 0..6399
  int lane = threadIdx.x & 63;
  int dir  = wid / (N_B * G0N);
  int r    = wid - dir * (N_B * G0N);
  const float* row = (dir ? simT : sim) + (size_t)r * G0N;
  int* out = (dir ? i10 : i01) + r * TK;

  float v[25];
#pragma unroll
  for (int tt = 0; tt < 25; ++tt) v[tt] = row[lane + 64 * tt];

#pragma unroll 1
  for (int k = 0; k < TK; ++k) {
    float best = -3.4e38f; int bidx = 0x7fffffff;
#pragma unroll
    for (int tt = 0; tt < 25; ++tt) {
      if (v[tt] > best) { best = v[tt]; bidx = lane + 64 * tt; }
    }
#pragma unroll
    for (int off = 1; off < 64; off <<= 1) {
      float ov = __shfl_xor(best, off);
      int   oi = __shfl_xor(bidx, off);
      if (ov > best || (ov == best && oi < bidx)) { best = ov; bidx = oi; }
    }
    if (lane == 0) out[k] = bidx;
#pragma unroll
    for (int tt = 0; tt < 25; ++tt)
      if (lane + 64 * tt == bidx) v[tt] = -3.4e38f;
  }
}

// ---------------- K3: pre-softmax heatmaps, direct-global, no LDS ----------------
// Block 256 = one (d, ng). Thread (q, ch, k4); each lane streams its own 512B att seg.
__global__ __launch_bounds__(256) void k_heat3(const float* __restrict__ x0,
                                               const float* __restrict__ a01,
                                               const float* __restrict__ x1,
                                               const float* __restrict__ a10,
                                               float* __restrict__ h01p,
                                               float* __restrict__ h10p) {
  const int bid = blockIdx.x;
  const int d   = bid / 3200;
  const int ng  = bid - d * 3200;
  const float* xp = (d ? x1  : x0)  + (size_t)ng * 4  * C_DIM;
  const float* ap = (d ? a10 : a01) + (size_t)ng * 32 * C_DIM;
  float*       hp = (d ? h10p : h01p);

  const int t = threadIdx.x;
  const int q = t >> 6, lane = t & 63;
  const int k4 = lane & 31, ch = lane >> 5;
  const float4* av = (const float4*)(ap + k4 * C_DIM + ch * 128);
  const float4* xv = (const float4*)(xp + q  * C_DIM + ch * 128);  // uniform per half-wave
  float acc = 0.f;
#pragma unroll
  for (int c = 0; c < 32; ++c) {
    float4 a = av[c];
    float4 x = xv[c];
    acc += a.x * x.x + a.y * x.y + a.z * x.z + a.w * x.w;
  }
  acc += __shfl_xor(acc, 32);  // combine C halves

  float l = (acc * (1.0f / 256.0f)) / 0.1f;  // /C then /TEMP (reference order)
  float m = l;
#pragma unroll
  for (int off = 1; off < 32; off <<= 1) m = fmaxf(m, __shfl_xor(m, off));
  float e = expf(l - m);
  float s = e;
#pragma unroll
  for (int off = 1; off < 32; off <<= 1) s += __shfl_xor(s, off);
  if (ch == 0) hp[(size_t)ng * 128 + q * 32 + k4] = e / s;
}

// ---------------- K4: fused mutual heatmaps + argmax (both directions) ----------------
__global__ __launch_bounds__(256) void k_fuse(const float* __restrict__ h01p,
                                              const float* __restrict__ h10p,
                                              const int* __restrict__ i01,
                                              const int* __restrict__ i10,
                                              float* __restrict__ h01_out,
                                              float* __restrict__ h10_out,
                                              float* __restrict__ score_ws,
                                              int* __restrict__ jbest_ws,
                                              float* __restrict__ jbest_out,
                                              int* __restrict__ ibest_ws) {
  const int d   = blockIdx.x / 1600;
  const int sub = blockIdx.x - d * 1600;
  int idx = sub * 8 + (threadIdx.x >> 5);  // (n, l)
  int k4  = threadIdx.x & 31;
  int n = idx / L0N, l = idx - n * L0N;
  int rr = l / W_F, cc = l - rr * W_F;
  int g = (rr >> 1) * GW + (cc >> 1);
  int q = ((rr & 1) << 1) | (cc & 1);
  int k = k4 >> 2, gg = k4 & 3;

  if (d == 0) {
    int jc = i01[(n * G0N + g) * TK + k];
    const int* row10 = i10 + (n * G0N + jc) * TK;
    int kf = -1;
#pragma unroll
    for (int kp = 0; kp < 8; ++kp) if (row10[kp] == g) kf = kp;
    float m = 0.f;
    if (kf >= 0) m = h10p[((n * G0N + jc) * 4 + gg) * 32 + kf * 4 + q];
    float h = h01p[((n * G0N + g) * 4 + q) * 32 + k4];
    float val = h * m;
    h01_out[(size_t)idx * 32 + k4] = val;

    float best = val; int bi = k4;
#pragma unroll
    for (int off = 1; off < 32; off <<= 1) {
      float ov = __shfl_xor(best, off);
      int   oi = __shfl_xor(bi, off);
      if (ov > best || (ov == best && oi < bi)) { best = ov; bi = oi; }
    }
    if (k4 == 0) {
      score_ws[idx] = best;
      int kB = bi >> 2, gB = bi & 3;
      int jcB = i01[(n * G0N + g) * TK + kB];
      int jrow = jcB / GW;
      int jb = ((jrow * 2 + (gB >> 1)) * W_F) + (jcB - jrow * GW) * 2 + (gB & 1);
      if (rr < 2 || rr >= W_F - 2 || cc < 2 || cc >= W_F - 2) jb = 0;
      jbest_ws[idx]  = jb;
      jbest_out[idx] = (float)jb;
    }
  } else {
    int ic = i10[(n * G0N + g) * TK + k];
    const int* row01 = i01 + (n * G0N + ic) * TK;
    int kf = -1;
#pragma unroll
    for (int kp = 0; kp < 8; ++kp) if (row01[kp] == g) kf = kp;
    float m = 0.f;
    if (kf >= 0) m = h01p[((n * G0N + ic) * 4 + gg) * 32 + kf * 4 + q];
    float h = h10p[((n * G0N + g) * 4 + q) * 32 + k4];
    float val = h * m;
    h10_out[((size_t)n * 32 + k4) * L0N + l] = val;

    float best = val; int bi = k4;
#pragma unroll
    for (int off = 1; off < 32; off <<= 1) {
      float ov = __shfl_xor(best, off);
      int   oi = __shfl_xor(bi, off);
      if (ov > best || (ov == best && oi < bi)) { best = ov; bi = oi; }
    }
    if (k4 == 0) {
      int kB = bi >> 2, gB = bi & 3;
      int icB = i10[(n * G0N + g) * TK + kB];
      int irow = icB / GW;
      int ib = ((irow * 2 + (gB >> 1)) * W_F) + (icB - irow * GW) * 2 + (gB & 1);
      if (rr < 2 || rr >= W_F - 2 || cc < 2 || cc >= W_F - 2) ib = 0;
      ibest_ws[idx] = ib;
    }
  }
}

// ---------------- K5: bi-projection mask + masked scores ----------------
__global__ __launch_bounds__(256) void k_final(const float* __restrict__ score_ws,
                                               const int* __restrict__ jbest_ws,
                                               const int* __restrict__ ibest_ws,
                                               float* __restrict__ scores_out,
                                               float* __restrict__ mask_out) {
  int idx = blockIdx.x * 256 + threadIdx.x;
  if (idx >= N_B * L0N) return;
  int n = idx / L0N, l0 = idx - n * L0N;
  int jb = jbest_ws[idx];
  float sc = score_ws[idx];
  int biproj = ibest_ws[n * L0N + jb];
  bool mk = (biproj == l0) && (l0 != 0) && (sc > 0.2f);
  scores_out[idx] = mk ? sc : 0.f;
  mask_out[idx]   = mk ? 1.f : 0.f;
}

// ---------------- K6: unpatchify, both tensors in one dispatch ----------------
__global__ __launch_bounds__(256) void k_unpatch2(const float* __restrict__ x0,
                                                  const float* __restrict__ x1,
                                                  float* __restrict__ o0,
                                                  float* __restrict__ o1) {
  __shared__ float tile[32][33];
  int which = blockIdx.z >> 4;
  const float* x = which ? x1 : x0;
  float* out = which ? o1 : o0;
  int zz  = blockIdx.z & 15;
  int cc0 = blockIdx.x * 32;
  int r   = blockIdx.y;
  int n   = zz >> 3;
  int c0  = (zz & 7) * 32;
  int t = threadIdx.x;
  int sr = r & 1, ghr = r >> 1;
  int pos = t >> 5, cl = t & 31;
#pragma unroll
  for (int it = 0; it < 4; ++it) {
    int p = pos + it * 8;
    int cc = cc0 + p;
    if (cc < W_F) {
      int gg = ghr * GW + (cc >> 1);
      int qq = (sr << 1) | (cc & 1);
      tile[p][cl] = x[(((size_t)n * G0N + gg) * 4 + qq) * C_DIM + c0 + cl];
    }
  }
  __syncthreads();
  int co = t >> 5, p2 = t & 31;
#pragma unroll
  for (int it = 0; it < 4; ++it) {
    int c = c0 + co + it * 8;
    int cc = cc0 + p2;
    if (cc < W_F)
      out[(((size_t)n * C_DIM + c) * W_F + r) * W_F + cc] = tile[p2][co + it * 8];
  }
}

extern "C" void kernel_launch(void* const* d_in, const int* in_sizes, int n_in,
                              void* d_out, int out_size, void* d_ws, size_t ws_size,
                              hipStream_t stream) {
  const float* x0  = (const float*)d_in[0];
  const float* x1  = (const float*)d_in[1];
  const float* a01 = (const float*)d_in[2];
  const float* a10 = (const float*)d_in[3];
  const float* p0  = (const float*)d_in[4];
  const float* p1  = (const float*)d_in[5];
  float* out = (float*)d_out;

  float* ws       = (float*)d_ws;
  float* sim      = ws;                      // 2*1600*1600
  float* simT     = ws + 5120000;            // 2*1600*1600
  int*   i01      = (int*)(ws + 10240000);   // 2*1600*8
  int*   i10      = (int*)(ws + 10265600);
  float* h01p     = ws + 10291200;           // 2*1600*4*32
  float* h10p     = ws + 10700800;
  float* score_ws = ws + 11110400;           // 2*6400
  int*   jbest_ws = (int*)(ws + 11123200);
  int*   ibest_ws = (int*)(ws + 11136000);

  float* o_h01   = out;
  float* o_h10   = out + 409600;
  float* o_score = out + 819200;
  float* o_jbest = out + 832000;
  float* o_mask  = out + 844800;
  float* o_x08   = out + 857600;
  float* o_x18   = out + 4134400;

  k_sim3<<<dim3(13, 13, 2), 256, 0, stream>>>(p0, p1, sim, simT);
  k_topk<<<1600, 256, 0, stream>>>(sim, simT, i01, i10);
  k_heat3<<<6400, 256, 0, stream>>>(x0, a01, x1, a10, h01p, h10p);
  k_fuse<<<3200, 256, 0, stream>>>(h01p, h10p, i01, i10,
                                   o_h01, o_h10, score_ws, jbest_ws, o_jbest, ibest_ws);
  k_final<<<50, 256, 0, stream>>>(score_ws, jbest_ws, ibest_ws, o_score, o_mask);
  k_unpatch2<<<dim3(3, 80, 32), 256, 0, stream>>>(x0, x1, o_x08, o_x18);
}